// Round 6
// baseline (294.735 us; speedup 1.0000x reference)
//
#include <hip/hip_runtime.h>
#include <hip/hip_bf16.h>

// SpectralConv3d: closed-form separable transforms (no FFT needed).
// fwd:  X[bc,k1,k2,k3] = sum_{j1,j2,j3} T[k1,j1]T[k2,j2]T[k3,j3] x[bc,j1,j2,j3]
//       T[k,j] = w_j cos(2*pi*j*k/126), w_0=w_63=1 else 2   (k<16, j<64)
// mix:  low[b,o,m] = sum_i X[b,i,m] W[i,o,m]
// inv:  E (p1, cosA) -> U (LDS);  F (p2, cosA) + G (p3, cosB/sinB) -> out
//       cosA[p,j]=cos(2pi j p/64)/64 (p<33), cosB/sinB[p,j]=cos/sin(2pi j p/33)/33 (p<17)

#define PI2 6.283185307179586476925f

// ---------------- init: transform matrices into workspace ----------------
__global__ void k_init(float* __restrict__ Tmat, float* __restrict__ cA,
                       float* __restrict__ cB, float* __restrict__ sB) {
    int t = blockIdx.x * 256 + threadIdx.x;
    if (t < 1024) {
        int k = t >> 6, j = t & 63;
        float w = (j == 0 || j == 63) ? 1.f : 2.f;
        int r = (j * k) % 126;
        Tmat[t] = w * cosf(PI2 * (float)r / 126.f);
    }
    if (t < 528) {
        int p = t >> 4, j = t & 15;
        int r = (j * p) % 64;
        cA[t] = cosf(PI2 * (float)r / 64.f) * (1.f / 64.f);
    }
    if (t < 272) {
        int p = t >> 4, j = t & 15;
        int r = (j * p) % 33;
        float a = PI2 * (float)r / 33.f;
        cB[t] = cosf(a) * (1.f / 33.f);
        sB[t] = sinf(a) * (1.f / 33.f);
    }
}

// ---------------- fused forward: contract j3 then j2 ----------------
// A2[bc][j1][k2][k3] = sum_{j2,j3} x[bc,j1,j2,j3] T[k3,j3] T[k2,j2]
// Block = (bc, j1-octet): 8 j1 slabs pipelined with register prefetch so load
// latency is amortized; 1024 blocks x 256 thr, 26KB LDS.
__global__ __launch_bounds__(256) void k_fwd12(const float* __restrict__ x,
                                               const float* __restrict__ Tmat,
                                               float* __restrict__ A2) {
    __shared__ float xb[64 * 68];   // padded rows (stride 17 float4)
    __shared__ float Ts[16 * 68];   // padded T for phase 2
    __shared__ float tmp[16 * 68];  // tmp[k3][j2]
    const int oct = blockIdx.x, bc = blockIdx.y;
    const int t = threadIdx.x;
    const int j2 = t & 63;
    const int gu = t >> 6;  // wave index 0..3 (wave-uniform by construction)

    float4* xb4 = (float4*)xb;
    float4* Ts4 = (float4*)Ts;
    const float4* Tg4 = (const float4*)Tmat;

    // stage padded T once (256 float4)
    Ts4[(t >> 4) * 17 + (t & 15)] = Tg4[t];

    // prefetch slab jj=0 (coalesced: consecutive lanes -> consecutive float4)
    const float4* xg = (const float4*)x + ((size_t)(bc * 64 + oct * 8)) * 1024;
    float4 pf[4];
#pragma unroll
    for (int i = 0; i < 4; i++) pf[i] = xg[t + 256 * i];

    for (int jj = 0; jj < 8; jj++) {
        // write prefetched slab into padded LDS
#pragma unroll
        for (int i = 0; i < 4; i++) {
            int idx = t + 256 * i;
            xb4[(idx >> 4) * 17 + (idx & 15)] = pf[i];
        }
        __syncthreads();

        // prefetch next slab while computing this one
        if (jj < 7) {
            const float4* xn = xg + (size_t)(jj + 1) * 1024;
#pragma unroll
            for (int i = 0; i < 4; i++) pf[i] = xn[t + 256 * i];
        }

        // phase 1: tmp[k3][j2] = sum_j3 xb[j2][j3] * T[k3][j3], k3 = 4*gu+c
        float acc[4] = {0.f, 0.f, 0.f, 0.f};
#pragma unroll
        for (int q = 0; q < 16; q++) {
            float4 xv = xb4[j2 * 17 + q];
#pragma unroll
            for (int c = 0; c < 4; c++) {
                float4 tv = Ts4[(4 * gu + c) * 17 + q];
                acc[c] += xv.x * tv.x + xv.y * tv.y + xv.z * tv.z + xv.w * tv.w;
            }
        }
#pragma unroll
        for (int c = 0; c < 4; c++) tmp[(4 * gu + c) * 68 + j2] = acc[c];
        __syncthreads();

        // phase 2: A2[k2][k3] = sum_j2 tmp[k3][j2] * T[k2][j2]
        // k3 = t&15, k2 = t>>4; both LDS streams are 16-address broadcasts.
        {
            const int k3 = t & 15, k2 = t >> 4;
            const float4* tmp4 = (const float4*)tmp;
            float a2 = 0.f;
#pragma unroll
            for (int q = 0; q < 16; q++) {
                float4 tv = tmp4[k3 * 17 + q];
                float4 Tv = Ts4[k2 * 17 + q];
                a2 += tv.x * Tv.x + tv.y * Tv.y + tv.z * Tv.z + tv.w * Tv.w;
            }
            A2[((size_t)bc * 64 + oct * 8 + jj) * 256 + t] = a2;  // t == k2*16+k3
        }
        // next iteration's xb/tmp writes are ordered by the loop-top barrier
    }
}

// ---------------- forward j1 contraction ----------------
// X[bc][k1][m] = sum_j1 A2[bc][j1][m] * T[k1][j1]
// One block per bc; thread owns all 16 k1 -> A2 read exactly once (8 MB).
__global__ __launch_bounds__(256) void k_fwd3(const float* __restrict__ A2,
                                              const float* __restrict__ Tmat,
                                              float* __restrict__ X) {
    const int bc = blockIdx.x;
    const int t = threadIdx.x;  // m
    const float* Ap = A2 + (size_t)bc * 16384 + t;
    float acc[16];
#pragma unroll
    for (int k = 0; k < 16; k++) acc[k] = 0.f;
#pragma unroll 4
    for (int j1 = 0; j1 < 64; j1++) {
        float v = Ap[j1 * 256];
#pragma unroll
        for (int k = 0; k < 16; k++) acc[k] += v * Tmat[k * 64 + j1];
    }
    float* Xp = X + (size_t)bc * 4096 + t;
#pragma unroll
    for (int k = 0; k < 16; k++) Xp[k * 256] = acc[k];
}

// ---------------- channel mix ----------------
// low[b,o,m] = sum_i X[b*32+i][m] * W[(i*32+o)][m]; W read exactly once.
__global__ __launch_bounds__(256) void k_mix(const float* __restrict__ X,
                                             const float* __restrict__ W,
                                             float* __restrict__ low) {
    const int mc = blockIdx.x;  // 0..15
    const int o = blockIdx.y;   // 0..31
    const int m = mc * 256 + threadIdx.x;
    const float* Xp = X + m;
    const float* Wp = W + (size_t)o * 4096 + m;
    float acc[4] = {0.f, 0.f, 0.f, 0.f};
#pragma unroll 4
    for (int i = 0; i < 32; i++) {
        float wv = Wp[(size_t)i * 32 * 4096];
#pragma unroll
        for (int b = 0; b < 4; b++)
            acc[b] += Xp[(size_t)(b * 32 + i) * 4096] * wv;
    }
#pragma unroll
    for (int b = 0; b < 4; b++)
        low[((size_t)(b * 32 + o)) * 4096 + m] = acc[b];
}

// ---------------- fused inverse per bo: E in LDS, then loop p1 {F, G} -------
__global__ __launch_bounds__(256) void k_inv(const float* __restrict__ low,
                                             const float* __restrict__ cA,
                                             const float* __restrict__ cB,
                                             const float* __restrict__ sB,
                                             float* __restrict__ out) {
    __shared__ float U1[33 * 256];  // E output, stays in LDS
    __shared__ float c2[528];
    __shared__ float cAs[528], cBs[272], sBs[272];
    const int bo = blockIdx.x;
    const int t = threadIdx.x;

    for (int c = t; c < 528; c += 256) cAs[c] = cA[c];
    for (int c = t; c < 272; c += 256) { cBs[c] = cB[c]; sBs[c] = sB[c]; }

    // E: U1[p1][t] = sum_k1 low[bo][k1][t] * cosA[p1][k1]; thread owns m = t.
    const float* lp = low + (size_t)bo * 4096 + t;
    float lr[16];
#pragma unroll
    for (int k1 = 0; k1 < 16; k1++) lr[k1] = lp[k1 << 8];
    __syncthreads();  // cAs ready
#pragma unroll 1
    for (int p1 = 0; p1 < 33; p1++) {
        float a0 = 0.f, a1 = 0.f, a2 = 0.f, a3 = 0.f;
#pragma unroll
        for (int k1 = 0; k1 < 16; k1 += 4) {
            a0 += lr[k1] * cAs[p1 * 16 + k1];
            a1 += lr[k1 + 1] * cAs[p1 * 16 + k1 + 1];
            a2 += lr[k1 + 2] * cAs[p1 * 16 + k1 + 2];
            a3 += lr[k1 + 3] * cAs[p1 * 16 + k1 + 3];
        }
        U1[p1 * 256 + t] = (a0 + a1) + (a2 + a3);
    }
    __syncthreads();

    float* op = out + (size_t)bo * 33 * 1122;
#pragma unroll 1
    for (int p1 = 0; p1 < 33; p1++) {
        // F: c2[p2*16+k3] = sum_k2 U1[p1][k2*16+k3] * cosA[p2][k2]
        for (int idx = t; idx < 528; idx += 256) {
            int p2 = idx >> 4, k3 = idx & 15;
            float acc = 0.f;
#pragma unroll
            for (int k2 = 0; k2 < 16; k2++)
                acc += U1[p1 * 256 + (k2 << 4) + k3] * cAs[p2 * 16 + k2];
            c2[idx] = acc;
        }
        __syncthreads();

        // G: out[p1][p2][p3][{re,im}] = sum_k3 c2[p2][k3] * cosB/sinB[p3][k3]
        for (int idx = t; idx < 1122; idx += 256) {
            int p2 = idx / 34, rem = idx % 34;
            int p3 = rem >> 1, cc = rem & 1;
            const float* M = cc ? sBs : cBs;
            float acc = 0.f;
#pragma unroll
            for (int k3 = 0; k3 < 16; k3++)
                acc += c2[(p2 << 4) + k3] * M[p3 * 16 + k3];
            op[p1 * 1122 + idx] = acc;
        }
        __syncthreads();  // protect c2 before next p1 overwrites it
    }
}

extern "C" void kernel_launch(void* const* d_in, const int* in_sizes, int n_in,
                              void* d_out, int out_size, void* d_ws, size_t ws_size,
                              hipStream_t stream) {
    const float* x = (const float*)d_in[0];   // (4,32,64,64,64)
    const float* W = (const float*)d_in[1];   // (32,32,16,16,16)
    float* out = (float*)d_out;               // (4,32,33,33,17,2)

    float* ws = (float*)d_ws;
    float* Tmat = ws;                 // 1024
    float* cA   = ws + 1024;          // 528
    float* cB   = ws + 1552;          // 272
    float* sB   = ws + 1824;          // 272
    float* A2   = ws + 4096;          // 128*64*256 = 2097152
    float* X    = A2 + 2097152;       // 128*4096   = 524288
    float* low  = X + 524288;         // 128*4096   = 524288

    k_init<<<dim3(4), dim3(256), 0, stream>>>(Tmat, cA, cB, sB);
    k_fwd12<<<dim3(8, 128), dim3(256), 0, stream>>>(x, Tmat, A2);
    k_fwd3<<<dim3(128), dim3(256), 0, stream>>>(A2, Tmat, X);
    k_mix<<<dim3(16, 32), dim3(256), 0, stream>>>(X, W, low);
    k_inv<<<dim3(128), dim3(256), 0, stream>>>(low, cA, cB, sB, out);
}